// Round 2
// baseline (2817.221 us; speedup 1.0000x reference)
//
#include <hip/hip_runtime.h>
#include <hip/hip_bf16.h>
#include <math.h>

#define DST_PER_BUCKET 32
#define BSHIFT 5
#define BMASK 31

// ---------------- degree histogram ----------------
__global__ void k_hist(const int* __restrict__ dst, int* __restrict__ deg, int nE) {
    for (int e = blockIdx.x * blockDim.x + threadIdx.x; e < nE; e += gridDim.x * blockDim.x) {
        atomicAdd(&deg[dst[e]], 1);
    }
}

// ---------------- bucket scan: bbase/bcursor from deg; dinv ----------------
__global__ void k_scan(const int* __restrict__ deg, int* __restrict__ bbase,
                       int* __restrict__ bcursor, float* __restrict__ dinv,
                       int n, int nE, int nb) {
    __shared__ int sums[1024];
    int t = threadIdx.x;
    int cnt[4];
    int s = 0;
#pragma unroll
    for (int j = 0; j < 4; ++j) {
        int bi = t * 4 + j;
        int c = 0;
        if (bi < nb) {
            int lo = bi * DST_PER_BUCKET;
            int hi = min(n, lo + DST_PER_BUCKET);
            for (int i = lo; i < hi; ++i) c += deg[i];
        }
        cnt[j] = c;
        s += c;
    }
    sums[t] = s;
    __syncthreads();
    for (int d = 1; d < 1024; d <<= 1) {
        int v = (t >= d) ? sums[t - d] : 0;
        __syncthreads();
        sums[t] += v;
        __syncthreads();
    }
    int run = sums[t] - s;  // exclusive prefix
#pragma unroll
    for (int j = 0; j < 4; ++j) {
        int bi = t * 4 + j;
        if (bi < nb) {
            bbase[bi] = run;
            bcursor[bi] = run;
            run += cnt[j];
        }
    }
    if (t == 0) bbase[nb] = nE;
    for (int i = t; i < n; i += 1024) dinv[i] = rsqrtf((float)(deg[i] + 1));
}

// ---------------- bucket fill: packed (src | dst_local<<17) append ----------------
__global__ void k_fill(const int* __restrict__ src, const int* __restrict__ dst,
                       int* __restrict__ bcursor, int* __restrict__ bucketed, int nE) {
    for (int e = blockIdx.x * blockDim.x + threadIdx.x; e < nE; e += gridDim.x * blockDim.x) {
        int d = dst[e];
        int entry = src[e] | ((d & BMASK) << 17);
        int pos = atomicAdd(&bcursor[d >> BSHIFT], 1);
        bucketed[pos] = entry;
    }
}

// ---------------- conv (block per bucket, LDS accumulate) ----------------
// MODE 0: GCN  h = tanh((dinv_i * sum(dinv_s * x_s) + dinv_i^2 * x_i) @ Wa + ba)
// MODE 1: SAGE + tanh; MODE 2: SAGE plain
//   SAGE: y = mean_agg @ Wa + ba + x_i @ Wb; y = y / max(||y||, eps)
template <int MODE>
__global__ void k_conv(const float* __restrict__ hin, const int* __restrict__ bucketed,
                       const int* __restrict__ bbase, const int* __restrict__ deg,
                       const float* __restrict__ dinv,
                       const float* __restrict__ Wa, const float* __restrict__ ba,
                       const float* __restrict__ Wb,
                       float* __restrict__ hout, int n) {
    __shared__ float acc[DST_PER_BUCKET][17];  // padded: LDS-atomic bank spread
    int b = blockIdx.x;
    int t = threadIdx.x;  // 256
    for (int i = t; i < DST_PER_BUCKET * 17; i += 256) ((float*)acc)[i] = 0.f;
    __syncthreads();

    int e0 = bbase[b], e1 = bbase[b + 1];
    int lane = t & 63;
    int f = lane & 15;

    for (int base = e0; base < e1; base += 256) {
        int e = base + t;
        int entry = (e < e1) ? bucketed[e] : -1;
#pragma unroll
        for (int r = 0; r < 16; ++r) {
            int ent = __shfl(entry, (lane & 48) | r);
            if (ent >= 0) {
                int s = ent & 0x1FFFF;
                int dl = (ent >> 17) & BMASK;
                float val = hin[s * 16 + f];
                if (MODE == 0) val *= dinv[s];
                atomicAdd(&acc[dl][f], val);
            }
        }
    }
    __syncthreads();

    // epilogue: 8 threads per node, 2 output features each
    int node_l = t >> 3;
    int fp = (t & 7) * 2;
    int i = b * DST_PER_BUCKET + node_l;
    if (i >= n) return;

    float h[16];
    const float4* hp = (const float4*)(hin + i * 16);
#pragma unroll
    for (int q = 0; q < 4; ++q) {
        float4 v = hp[q];
        h[q * 4 + 0] = v.x; h[q * 4 + 1] = v.y; h[q * 4 + 2] = v.z; h[q * 4 + 3] = v.w;
    }

    float y0, y1;
    if (MODE == 0) {
        float di = dinv[i];
        float di2 = di * di;
        y0 = ba[fp]; y1 = ba[fp + 1];
#pragma unroll
        for (int k = 0; k < 16; ++k) {
            float a = di * acc[node_l][k] + di2 * h[k];
            y0 += a * Wa[k * 16 + fp];
            y1 += a * Wa[k * 16 + fp + 1];
        }
        y0 = tanhf(y0); y1 = tanhf(y1);
    } else {
        float inv = 1.0f / fmaxf((float)deg[i], 1.0f);
        y0 = ba[fp]; y1 = ba[fp + 1];
#pragma unroll
        for (int k = 0; k < 16; ++k) {
            float a = acc[node_l][k] * inv;
            y0 += a * Wa[k * 16 + fp] + h[k] * Wb[k * 16 + fp];
            y1 += a * Wa[k * 16 + fp + 1] + h[k] * Wb[k * 16 + fp + 1];
        }
        float sq = y0 * y0 + y1 * y1;
        sq += __shfl_xor(sq, 1);
        sq += __shfl_xor(sq, 2);
        sq += __shfl_xor(sq, 4);
        float nrm = fmaxf(sqrtf(sq), 1e-12f);
        y0 /= nrm; y1 /= nrm;
        if (MODE == 1) { y0 = tanhf(y0); y1 = tanhf(y1); }
    }
    ((float2*)(hout + i * 16))[t & 7] = make_float2(y0, y1);
}

// ---------------- Fused MLP: 16 -> 128 -> 128 -> 1 (thread per node) ----------------
__global__ void k_mlp(const float* __restrict__ h3,
                      const float* __restrict__ W1, const float* __restrict__ b1,
                      const float* __restrict__ W2, const float* __restrict__ b2,
                      const float* __restrict__ W3, const float* __restrict__ b3,
                      float* __restrict__ out, int n) {
    int node = blockIdx.x * blockDim.x + threadIdx.x;
    if (node >= n) return;
    float h[16];
    const float4* hp = (const float4*)(h3 + node * 16);
    float4 v0 = hp[0], v1 = hp[1], v2 = hp[2], v3 = hp[3];
    h[0] = v0.x; h[1] = v0.y; h[2] = v0.z; h[3] = v0.w;
    h[4] = v1.x; h[5] = v1.y; h[6] = v1.z; h[7] = v1.w;
    h[8] = v2.x; h[9] = v2.y; h[10] = v2.z; h[11] = v2.w;
    h[12] = v3.x; h[13] = v3.y; h[14] = v3.z; h[15] = v3.w;

    float t1[128];
#pragma unroll
    for (int j = 0; j < 128; ++j) {
        float acc = b1[j];
#pragma unroll
        for (int k = 0; k < 16; ++k) acc += h[k] * W1[k * 128 + j];
        t1[j] = fmaxf(acc, 0.f);
    }

    float out3 = b3[0];
    for (int jc = 0; jc < 8; ++jc) {
        float acc[16];
#pragma unroll
        for (int j = 0; j < 16; ++j) acc[j] = b2[jc * 16 + j];
#pragma unroll
        for (int k = 0; k < 128; ++k) {
            float tk = t1[k];
#pragma unroll
            for (int j = 0; j < 16; ++j) acc[j] += tk * W2[k * 128 + jc * 16 + j];
        }
#pragma unroll
        for (int j = 0; j < 16; ++j) out3 += fmaxf(acc[j], 0.f) * W3[jc * 16 + j];
    }
    out[node] = out3;
}

// ---------------- launch ----------------
extern "C" void kernel_launch(void* const* d_in, const int* in_sizes, int n_in,
                              void* d_out, int out_size, void* d_ws, size_t ws_size,
                              hipStream_t stream) {
    const float* x = (const float*)d_in[0];
    const int* ei = (const int*)d_in[1];
    const float* W_gcn = (const float*)d_in[2];
    const float* b_gcn = (const float*)d_in[3];
    const float* Wl1 = (const float*)d_in[4];
    const float* bl1 = (const float*)d_in[5];
    const float* Wr1 = (const float*)d_in[6];
    const float* Wl2 = (const float*)d_in[7];
    const float* bl2 = (const float*)d_in[8];
    const float* Wr2 = (const float*)d_in[9];
    const float* W1 = (const float*)d_in[10];
    const float* b1 = (const float*)d_in[11];
    const float* W2 = (const float*)d_in[12];
    const float* b2 = (const float*)d_in[13];
    const float* W3 = (const float*)d_in[14];
    const float* b3 = (const float*)d_in[15];

    const int N = in_sizes[0] / 16;
    const int E = in_sizes[1] / 2;
    const int NB = (N + DST_PER_BUCKET - 1) / DST_PER_BUCKET;
    const int* src = ei;
    const int* dst = ei + E;

    char* w = (char*)d_ws;
    auto alloc = [&](size_t bytes) {
        void* p = (void*)w;
        w += (bytes + 255) & ~(size_t)255;
        return p;
    };
    int* deg = (int*)alloc((size_t)N * 4);
    float* dinv = (float*)alloc((size_t)N * 4);
    int* bbase = (int*)alloc((size_t)(NB + 1) * 4);
    int* bcursor = (int*)alloc((size_t)NB * 4);
    int* bucketed = (int*)alloc((size_t)E * 4);
    float* h1 = (float*)alloc((size_t)N * 16 * 4);
    float* h2 = (float*)alloc((size_t)N * 16 * 4);
    float* h3 = (float*)alloc((size_t)N * 16 * 4);

    hipMemsetAsync(deg, 0, (size_t)N * 4, stream);

    int blk = 256;
    int egrid = min(2048, (E + blk - 1) / blk);
    k_hist<<<egrid, blk, 0, stream>>>(dst, deg, E);
    k_scan<<<1, 1024, 0, stream>>>(deg, bbase, bcursor, dinv, N, E, NB);
    k_fill<<<egrid, blk, 0, stream>>>(src, dst, bcursor, bucketed, E);

    k_conv<0><<<NB, blk, 0, stream>>>(x,  bucketed, bbase, deg, dinv, W_gcn, b_gcn, W_gcn, h1, N);
    k_conv<1><<<NB, blk, 0, stream>>>(h1, bucketed, bbase, deg, dinv, Wl1, bl1, Wr1, h2, N);
    k_conv<2><<<NB, blk, 0, stream>>>(h2, bucketed, bbase, deg, dinv, Wl2, bl2, Wr2, h3, N);

    int mgrid = (N + blk - 1) / blk;
    k_mlp<<<mgrid, blk, 0, stream>>>(h3, W1, b1, W2, b2, W3, b3, (float*)d_out, N);
}

// Round 3
// 1531.631 us; speedup vs baseline: 1.8394x; 1.8394x over previous
//
#include <hip/hip_runtime.h>
#include <hip/hip_bf16.h>
#include <math.h>

#define DST_PER_BUCKET 32
#define BSHIFT 5
#define BMASK 31

// ---------------- degree histogram (in-degree per node) ----------------
__global__ void k_hist(const int* __restrict__ dst, int* __restrict__ deg, int nE) {
    for (int e = blockIdx.x * blockDim.x + threadIdx.x; e < nE; e += gridDim.x * blockDim.x) {
        atomicAdd(&deg[dst[e]], 1);
    }
}

// ---------------- scan: rowstart[N+1] (exclusive), bcursor, dinv ----------------
__global__ void k_scan(const int* __restrict__ deg, int* __restrict__ rowstart,
                       int* __restrict__ bcursor, float* __restrict__ dinv,
                       int n, int nE, int nb) {
    __shared__ int sums[1024];
    int t = threadIdx.x;
    int chunk = (n + 1023) >> 10;
    int lo = t * chunk;
    int hi = min(n, lo + chunk);
    int s = 0;
    for (int i = lo; i < hi; ++i) s += deg[i];
    sums[t] = s;
    __syncthreads();
    for (int d = 1; d < 1024; d <<= 1) {
        int v = (t >= d) ? sums[t - d] : 0;
        __syncthreads();
        sums[t] += v;
        __syncthreads();
    }
    int run = sums[t] - s;  // exclusive prefix for this chunk
    for (int i = lo; i < hi; ++i) {
        int d = deg[i];
        rowstart[i] = run;
        dinv[i] = rsqrtf((float)(d + 1));
        run += d;
    }
    if (t == 0) rowstart[n] = nE;
    __syncthreads();  // block-level fence: rowstart visible
    for (int bi = t; bi < nb; bi += 1024) bcursor[bi] = rowstart[bi * DST_PER_BUCKET];
}

// ---------------- bucket fill: packed (src | dst_local<<17) append ----------------
__global__ void k_fill(const int* __restrict__ src, const int* __restrict__ dst,
                       int* __restrict__ bcursor, int* __restrict__ bucketed, int nE) {
    for (int e = blockIdx.x * blockDim.x + threadIdx.x; e < nE; e += gridDim.x * blockDim.x) {
        int d = dst[e];
        int entry = src[e] | ((d & BMASK) << 17);
        int pos = atomicAdd(&bcursor[d >> BSHIFT], 1);
        bucketed[pos] = entry;
    }
}

// ---------------- bucket -> per-node CSR (block per bucket) ----------------
// Writes confined to the bucket's contiguous csr window -> full-line writebacks.
__global__ void k_sort(const int* __restrict__ bucketed, const int* __restrict__ rowstart,
                       int* __restrict__ csr, int n, int nE, int nb) {
    __shared__ int cur[DST_PER_BUCKET];
    int b = blockIdx.x;
    int t = threadIdx.x;
    int node0 = b * DST_PER_BUCKET;
    if (t < DST_PER_BUCKET) cur[t] = rowstart[min(node0 + t, n)];
    __syncthreads();
    int e0 = rowstart[node0];
    int e1 = (node0 + DST_PER_BUCKET <= n) ? rowstart[node0 + DST_PER_BUCKET] : nE;
    for (int e = e0 + t; e < e1; e += blockDim.x) {
        int entry = bucketed[e];
        int s = entry & 0x1FFFF;
        int dl = (entry >> 17) & BMASK;
        int pos = atomicAdd(&cur[dl], 1);
        csr[pos] = s;
    }
}

// ---------------- conv: wave per node, 16 edge-slots x 4 lanes x float4 ----------------
// MODE 0: GCN  h = tanh((dinv_i * sum(dinv_s * x_s) + dinv_i^2 * x_i) @ Wa + ba)
// MODE 1: SAGE + tanh; MODE 2: SAGE plain
template <int MODE>
__global__ void k_conv(const float* __restrict__ hin, const int* __restrict__ csr,
                       const int* __restrict__ rowstart, const float* __restrict__ dinv,
                       const float* __restrict__ Wa, const float* __restrict__ ba,
                       const float* __restrict__ Wb,
                       float* __restrict__ hout, int n) {
    int wid = (blockIdx.x * blockDim.x + threadIdx.x) >> 6;
    if (wid >= n) return;
    int lane = threadIdx.x & 63;
    int q = lane >> 2;   // edge slot 0..15
    int c = lane & 3;    // feature quad: features 4c..4c+3
    int r0 = rowstart[wid], r1 = rowstart[wid + 1];
    int cnt = r1 - r0;
    const int* p = csr + r0 + q;
    int my = (cnt > q) ? ((cnt - q + 15) >> 4) : 0;

    float av[4] = {0.f, 0.f, 0.f, 0.f};
    int s0 = (my > 0) ? p[0] : 0;
    int s1 = (my > 1) ? p[16] : 0;
    for (int t = 0; t < my; ++t) {
        int scur = s0;
        s0 = s1;
        s1 = (t + 2 < my) ? p[(t + 2) * 16] : 0;
        float w = (MODE == 0) ? dinv[scur] : 1.0f;
        float4 v = *(const float4*)(hin + scur * 16 + c * 4);
        av[0] += w * v.x; av[1] += w * v.y; av[2] += w * v.z; av[3] += w * v.w;
    }
    // reduce across the 16 edge slots (lane bits 2..5)
#pragma unroll
    for (int m = 4; m <= 32; m <<= 1) {
#pragma unroll
        for (int j = 0; j < 4; ++j) av[j] += __shfl_xor(av[j], m);
    }

    // self row (features 4c..4c+3)
    float4 hv4 = *(const float4*)(hin + wid * 16 + c * 4);
    float hvv[4] = {hv4.x, hv4.y, hv4.z, hv4.w};

    if (MODE == 0) {
        float di = dinv[wid];
        float di2 = di * di;
#pragma unroll
        for (int j = 0; j < 4; ++j) av[j] = di * av[j] + di2 * hvv[j];
    } else {
        float inv = 1.0f / fmaxf((float)cnt, 1.0f);
#pragma unroll
        for (int j = 0; j < 4; ++j) av[j] *= inv;
    }

    // epilogue GEMM: all 64 lanes, output feature fo = lane&15
    int fo = lane & 15;
    float y = ba[fo];
#pragma unroll
    for (int k = 0; k < 16; ++k) {
        float ak = __shfl(av[k & 3], k >> 2);  // static component, static lane
        y += ak * Wa[k * 16 + fo];
        if (MODE != 0) {
            float hk = __shfl(hvv[k & 3], k >> 2);
            y += hk * Wb[k * 16 + fo];
        }
    }
    if (MODE == 0) {
        y = tanhf(y);
    } else {
        float sq = y * y;
        sq += __shfl_xor(sq, 1);
        sq += __shfl_xor(sq, 2);
        sq += __shfl_xor(sq, 4);
        sq += __shfl_xor(sq, 8);
        float nrm = fmaxf(sqrtf(sq), 1e-12f);
        y /= nrm;
        if (MODE == 1) y = tanhf(y);
    }
    if ((lane >> 4) == 0) hout[wid * 16 + fo] = y;
}

// ---------------- Fused MLP: 16 -> 128 -> 128 -> 1 (thread per node) ----------------
__global__ void k_mlp(const float* __restrict__ h3,
                      const float* __restrict__ W1, const float* __restrict__ b1,
                      const float* __restrict__ W2, const float* __restrict__ b2,
                      const float* __restrict__ W3, const float* __restrict__ b3,
                      float* __restrict__ out, int n) {
    int node = blockIdx.x * blockDim.x + threadIdx.x;
    if (node >= n) return;
    float h[16];
    const float4* hp = (const float4*)(h3 + node * 16);
    float4 v0 = hp[0], v1 = hp[1], v2 = hp[2], v3 = hp[3];
    h[0] = v0.x; h[1] = v0.y; h[2] = v0.z; h[3] = v0.w;
    h[4] = v1.x; h[5] = v1.y; h[6] = v1.z; h[7] = v1.w;
    h[8] = v2.x; h[9] = v2.y; h[10] = v2.z; h[11] = v2.w;
    h[12] = v3.x; h[13] = v3.y; h[14] = v3.z; h[15] = v3.w;

    float t1[128];
#pragma unroll
    for (int j = 0; j < 128; ++j) {
        float acc = b1[j];
#pragma unroll
        for (int k = 0; k < 16; ++k) acc += h[k] * W1[k * 128 + j];
        t1[j] = fmaxf(acc, 0.f);
    }

    float out3 = b3[0];
    for (int jc = 0; jc < 8; ++jc) {  // runtime loop: W2 index uniform, acc/t1 static
        float acc[16];
#pragma unroll
        for (int j = 0; j < 16; ++j) acc[j] = b2[jc * 16 + j];
#pragma unroll
        for (int k = 0; k < 128; ++k) {
            float tk = t1[k];
#pragma unroll
            for (int j = 0; j < 16; ++j) acc[j] += tk * W2[k * 128 + jc * 16 + j];
        }
#pragma unroll
        for (int j = 0; j < 16; ++j) out3 += fmaxf(acc[j], 0.f) * W3[jc * 16 + j];
    }
    out[node] = out3;
}

// ---------------- launch ----------------
extern "C" void kernel_launch(void* const* d_in, const int* in_sizes, int n_in,
                              void* d_out, int out_size, void* d_ws, size_t ws_size,
                              hipStream_t stream) {
    const float* x = (const float*)d_in[0];
    const int* ei = (const int*)d_in[1];
    const float* W_gcn = (const float*)d_in[2];
    const float* b_gcn = (const float*)d_in[3];
    const float* Wl1 = (const float*)d_in[4];
    const float* bl1 = (const float*)d_in[5];
    const float* Wr1 = (const float*)d_in[6];
    const float* Wl2 = (const float*)d_in[7];
    const float* bl2 = (const float*)d_in[8];
    const float* Wr2 = (const float*)d_in[9];
    const float* W1 = (const float*)d_in[10];
    const float* b1 = (const float*)d_in[11];
    const float* W2 = (const float*)d_in[12];
    const float* b2 = (const float*)d_in[13];
    const float* W3 = (const float*)d_in[14];
    const float* b3 = (const float*)d_in[15];

    const int N = in_sizes[0] / 16;
    const int E = in_sizes[1] / 2;
    const int NB = (N + DST_PER_BUCKET - 1) / DST_PER_BUCKET;
    const int* src = ei;
    const int* dst = ei + E;

    char* w = (char*)d_ws;
    auto alloc = [&](size_t bytes) {
        void* p = (void*)w;
        w += (bytes + 255) & ~(size_t)255;
        return p;
    };
    int* deg = (int*)alloc((size_t)N * 4);
    float* dinv = (float*)alloc((size_t)N * 4);
    int* rowstart = (int*)alloc((size_t)(N + 1) * 4);
    int* bcursor = (int*)alloc((size_t)NB * 4);
    int* bucketed = (int*)alloc((size_t)E * 4);
    int* csr = (int*)alloc((size_t)E * 4);
    float* h1 = (float*)alloc((size_t)N * 16 * 4);
    float* h2 = (float*)alloc((size_t)N * 16 * 4);
    float* h3 = (float*)alloc((size_t)N * 16 * 4);

    hipMemsetAsync(deg, 0, (size_t)N * 4, stream);

    int blk = 256;
    int egrid = min(2048, (E + blk - 1) / blk);
    k_hist<<<egrid, blk, 0, stream>>>(dst, deg, E);
    k_scan<<<1, 1024, 0, stream>>>(deg, rowstart, bcursor, dinv, N, E, NB);
    k_fill<<<egrid, blk, 0, stream>>>(src, dst, bcursor, bucketed, E);
    k_sort<<<NB, blk, 0, stream>>>(bucketed, rowstart, csr, N, E, NB);

    long long conv_threads = (long long)N * 64;
    int ggrid = (int)((conv_threads + blk - 1) / blk);
    k_conv<0><<<ggrid, blk, 0, stream>>>(x,  csr, rowstart, dinv, W_gcn, b_gcn, W_gcn, h1, N);
    k_conv<1><<<ggrid, blk, 0, stream>>>(h1, csr, rowstart, dinv, Wl1, bl1, Wr1, h2, N);
    k_conv<2><<<ggrid, blk, 0, stream>>>(h2, csr, rowstart, dinv, Wl2, bl2, Wr2, h3, N);

    int mgrid = (N + blk - 1) / blk;
    k_mlp<<<mgrid, blk, 0, stream>>>(h3, W1, b1, W2, b2, W3, b3, (float*)d_out, N);
}

// Round 4
// 634.095 us; speedup vs baseline: 4.4429x; 2.4155x over previous
//
#include <hip/hip_runtime.h>
#include <hip/hip_bf16.h>
#include <math.h>

#define NBLK 512
#define MAXNC 512  // supports N up to 131072 (256 nodes per coarse bucket)

// ---------------- pass A: coarse histogram per block chunk ----------------
__global__ void k_hist(const int* __restrict__ dst, int* __restrict__ hist,
                       int nE, int nc, int chunk) {
    __shared__ int ch[MAXNC];
    int b = blockIdx.x, t = threadIdx.x;
    for (int i = t; i < nc; i += 256) ch[i] = 0;
    __syncthreads();
    int c0 = b * chunk, c1 = min(nE, c0 + chunk);
    for (int e = c0 + t; e < c1; e += 256) atomicAdd(&ch[dst[e] >> 8], 1);
    __syncthreads();
    for (int i = t; i < nc; i += 256) hist[b * nc + i] = ch[i];
}

// ---------------- pass B: per-(block,cb) offsets + cbase scan ----------------
__global__ void k_scan(const int* __restrict__ hist, int* __restrict__ off,
                       int* __restrict__ cbase, int* __restrict__ rowstart,
                       int nE, int nc, int n) {
    __shared__ int sc[512];
    int t = threadIdx.x;  // 512
    int run = 0;
    if (t < nc) {
#pragma unroll 8
        for (int b = 0; b < NBLK; ++b) {
            off[b * nc + t] = run;          // within-cb exclusive prefix for block b
            run += hist[b * nc + t];
        }
    }
    sc[t] = (t < nc) ? run : 0;             // run = total count of cb t
    __syncthreads();
    for (int d = 1; d < 512; d <<= 1) {
        int v = (t >= d) ? sc[t - d] : 0;
        __syncthreads();
        sc[t] += v;
        __syncthreads();
    }
    if (t < nc) cbase[t] = sc[t] - run;     // exclusive cross-cb base
    if (t == 0) { cbase[nc] = nE; rowstart[n] = nE; }
}

// ---------------- pass C: deterministic scatter into coarse buckets ----------------
__global__ void k_fill(const int* __restrict__ src, const int* __restrict__ dst,
                       const int* __restrict__ off, const int* __restrict__ cbase,
                       int* __restrict__ bucketed, int nE, int nc, int chunk) {
    __shared__ int cur[MAXNC];
    int b = blockIdx.x, t = threadIdx.x;
    for (int i = t; i < nc; i += 256) cur[i] = cbase[i] + off[b * nc + i];
    __syncthreads();
    int c0 = b * chunk, c1 = min(nE, c0 + chunk);
    for (int e = c0 + t; e < c1; e += 256) {
        int d = dst[e];
        int entry = src[e] | ((d & 255) << 17);
        int pos = atomicAdd(&cur[d >> 8], 1);
        bucketed[pos] = entry;
    }
}

// ---------------- pass D: within-bucket sort to per-node CSR + deg/rowstart/dinv ----------------
__global__ void k_fine(const int* __restrict__ bucketed, const int* __restrict__ cbase,
                       int* __restrict__ csr, int* __restrict__ rowstart,
                       float* __restrict__ dinv, int n) {
    __shared__ int cnt[256];
    __shared__ int lrs[256];
    __shared__ int cur[256];
    int cb = blockIdx.x, t = threadIdx.x;  // 256 threads
    int e0 = cbase[cb], e1 = cbase[cb + 1];
    cnt[t] = 0;
    __syncthreads();
    for (int e = e0 + t; e < e1; e += 256) atomicAdd(&cnt[(bucketed[e] >> 17) & 255], 1);
    __syncthreads();
    int my = cnt[t];
    lrs[t] = my;
    __syncthreads();
    for (int d = 1; d < 256; d <<= 1) {
        int v = (t >= d) ? lrs[t - d] : 0;
        __syncthreads();
        lrs[t] += v;
        __syncthreads();
    }
    int excl = lrs[t] - my;
    int node = cb * 256 + t;
    if (node < n) {
        rowstart[node] = e0 + excl;
        dinv[node] = rsqrtf((float)(my + 1));
    }
    cur[t] = e0 + excl;
    __syncthreads();
    for (int e = e0 + t; e < e1; e += 256) {
        int entry = bucketed[e];
        int pos = atomicAdd(&cur[(entry >> 17) & 255], 1);
        csr[pos] = entry & 0x1FFFF;
    }
}

// ---------------- conv: wave per node, 16 edge-slots x 4 lanes x float4 ----------------
// MODE 0: GCN  h = tanh((dinv_i * sum(dinv_s * x_s) + dinv_i^2 * x_i) @ Wa + ba)
// MODE 1: SAGE + tanh; MODE 2: SAGE plain
template <int MODE>
__global__ void k_conv(const float* __restrict__ hin, const int* __restrict__ csr,
                       const int* __restrict__ rowstart, const float* __restrict__ dinv,
                       const float* __restrict__ Wa, const float* __restrict__ ba,
                       const float* __restrict__ Wb,
                       float* __restrict__ hout, int n) {
    int wid = (blockIdx.x * blockDim.x + threadIdx.x) >> 6;
    if (wid >= n) return;
    int lane = threadIdx.x & 63;
    int q = lane >> 2;   // edge slot 0..15
    int c = lane & 3;    // feature quad
    int r0 = rowstart[wid], r1 = rowstart[wid + 1];
    int cnt = r1 - r0;
    const int* p = csr + r0 + q;
    int my = (cnt > q) ? ((cnt - q + 15) >> 4) : 0;

    float av[4] = {0.f, 0.f, 0.f, 0.f};
    int s0 = (my > 0) ? p[0] : 0;
    int s1 = (my > 1) ? p[16] : 0;
    for (int t = 0; t < my; ++t) {
        int scur = s0;
        s0 = s1;
        s1 = (t + 2 < my) ? p[(t + 2) * 16] : 0;
        float w = (MODE == 0) ? dinv[scur] : 1.0f;
        float4 v = *(const float4*)(hin + scur * 16 + c * 4);
        av[0] += w * v.x; av[1] += w * v.y; av[2] += w * v.z; av[3] += w * v.w;
    }
#pragma unroll
    for (int m = 4; m <= 32; m <<= 1) {
#pragma unroll
        for (int j = 0; j < 4; ++j) av[j] += __shfl_xor(av[j], m);
    }

    float4 hv4 = *(const float4*)(hin + wid * 16 + c * 4);
    float hvv[4] = {hv4.x, hv4.y, hv4.z, hv4.w};

    if (MODE == 0) {
        float di = dinv[wid];
        float di2 = di * di;
#pragma unroll
        for (int j = 0; j < 4; ++j) av[j] = di * av[j] + di2 * hvv[j];
    } else {
        float inv = 1.0f / fmaxf((float)cnt, 1.0f);
#pragma unroll
        for (int j = 0; j < 4; ++j) av[j] *= inv;
    }

    int fo = lane & 15;
    float y = ba[fo];
#pragma unroll
    for (int k = 0; k < 16; ++k) {
        float ak = __shfl(av[k & 3], k >> 2);
        y += ak * Wa[k * 16 + fo];
        if (MODE != 0) {
            float hk = __shfl(hvv[k & 3], k >> 2);
            y += hk * Wb[k * 16 + fo];
        }
    }
    if (MODE == 0) {
        y = tanhf(y);
    } else {
        float sq = y * y;
        sq += __shfl_xor(sq, 1);
        sq += __shfl_xor(sq, 2);
        sq += __shfl_xor(sq, 4);
        sq += __shfl_xor(sq, 8);
        float nrm = fmaxf(sqrtf(sq), 1e-12f);
        y /= nrm;
        if (MODE == 1) y = tanhf(y);
    }
    if ((lane >> 4) == 0) hout[wid * 16 + fo] = y;
}

// ---------------- Fused MLP: 16 -> 128 -> 128 -> 1 (thread per node) ----------------
__global__ void k_mlp(const float* __restrict__ h3,
                      const float* __restrict__ W1, const float* __restrict__ b1,
                      const float* __restrict__ W2, const float* __restrict__ b2,
                      const float* __restrict__ W3, const float* __restrict__ b3,
                      float* __restrict__ out, int n) {
    int node = blockIdx.x * blockDim.x + threadIdx.x;
    if (node >= n) return;
    float h[16];
    const float4* hp = (const float4*)(h3 + node * 16);
    float4 v0 = hp[0], v1 = hp[1], v2 = hp[2], v3 = hp[3];
    h[0] = v0.x; h[1] = v0.y; h[2] = v0.z; h[3] = v0.w;
    h[4] = v1.x; h[5] = v1.y; h[6] = v1.z; h[7] = v1.w;
    h[8] = v2.x; h[9] = v2.y; h[10] = v2.z; h[11] = v2.w;
    h[12] = v3.x; h[13] = v3.y; h[14] = v3.z; h[15] = v3.w;

    float t1[128];
#pragma unroll
    for (int j = 0; j < 128; ++j) {
        float acc = b1[j];
#pragma unroll
        for (int k = 0; k < 16; ++k) acc += h[k] * W1[k * 128 + j];
        t1[j] = fmaxf(acc, 0.f);
    }

    float out3 = b3[0];
    for (int jc = 0; jc < 8; ++jc) {
        float acc[16];
#pragma unroll
        for (int j = 0; j < 16; ++j) acc[j] = b2[jc * 16 + j];
#pragma unroll
        for (int k = 0; k < 128; ++k) {
            float tk = t1[k];
#pragma unroll
            for (int j = 0; j < 16; ++j) acc[j] += tk * W2[k * 128 + jc * 16 + j];
        }
#pragma unroll
        for (int j = 0; j < 16; ++j) out3 += fmaxf(acc[j], 0.f) * W3[jc * 16 + j];
    }
    out[node] = out3;
}

// ---------------- launch ----------------
extern "C" void kernel_launch(void* const* d_in, const int* in_sizes, int n_in,
                              void* d_out, int out_size, void* d_ws, size_t ws_size,
                              hipStream_t stream) {
    const float* x = (const float*)d_in[0];
    const int* ei = (const int*)d_in[1];
    const float* W_gcn = (const float*)d_in[2];
    const float* b_gcn = (const float*)d_in[3];
    const float* Wl1 = (const float*)d_in[4];
    const float* bl1 = (const float*)d_in[5];
    const float* Wr1 = (const float*)d_in[6];
    const float* Wl2 = (const float*)d_in[7];
    const float* bl2 = (const float*)d_in[8];
    const float* Wr2 = (const float*)d_in[9];
    const float* W1 = (const float*)d_in[10];
    const float* b1 = (const float*)d_in[11];
    const float* W2 = (const float*)d_in[12];
    const float* b2 = (const float*)d_in[13];
    const float* W3 = (const float*)d_in[14];
    const float* b3 = (const float*)d_in[15];

    const int N = in_sizes[0] / 16;
    const int E = in_sizes[1] / 2;
    const int NC = (N + 255) >> 8;
    const int chunk = (E + NBLK - 1) / NBLK;
    const int* src = ei;
    const int* dst = ei + E;

    char* w = (char*)d_ws;
    auto alloc = [&](size_t bytes) {
        void* p = (void*)w;
        w += (bytes + 255) & ~(size_t)255;
        return p;
    };
    int* hist = (int*)alloc((size_t)NBLK * NC * 4);
    int* off = (int*)alloc((size_t)NBLK * NC * 4);
    int* cbase = (int*)alloc((size_t)(NC + 1) * 4);
    int* rowstart = (int*)alloc((size_t)(N + 1) * 4);
    float* dinv = (float*)alloc((size_t)N * 4);
    int* bucketed = (int*)alloc((size_t)E * 4);
    int* csr = (int*)alloc((size_t)E * 4);
    float* h1 = (float*)alloc((size_t)N * 16 * 4);
    float* h2 = (float*)alloc((size_t)N * 16 * 4);
    float* h3 = (float*)alloc((size_t)N * 16 * 4);

    k_hist<<<NBLK, 256, 0, stream>>>(dst, hist, E, NC, chunk);
    k_scan<<<1, 512, 0, stream>>>(hist, off, cbase, rowstart, E, NC, N);
    k_fill<<<NBLK, 256, 0, stream>>>(src, dst, off, cbase, bucketed, E, NC, chunk);
    k_fine<<<NC, 256, 0, stream>>>(bucketed, cbase, csr, rowstart, dinv, N);

    long long conv_threads = (long long)N * 64;
    int blk = 256;
    int ggrid = (int)((conv_threads + blk - 1) / blk);
    k_conv<0><<<ggrid, blk, 0, stream>>>(x,  csr, rowstart, dinv, W_gcn, b_gcn, W_gcn, h1, N);
    k_conv<1><<<ggrid, blk, 0, stream>>>(h1, csr, rowstart, dinv, Wl1, bl1, Wr1, h2, N);
    k_conv<2><<<ggrid, blk, 0, stream>>>(h2, csr, rowstart, dinv, Wl2, bl2, Wr2, h3, N);

    int mgrid = (N + blk - 1) / blk;
    k_mlp<<<mgrid, blk, 0, stream>>>(h3, W1, b1, W2, b2, W3, b3, (float*)d_out, N);
}